// Round 4
// baseline (595.648 us; speedup 1.0000x reference)
//
#include <hip/hip_runtime.h>
#include <hip/hip_bf16.h>

// Problem constants (from reference)
#define D_DIM 1024
#define H_DIMN 1024
#define N_TOK 1024   // B*M = 64*16
#define N_EXP 16
#define TOPK  4
#define N_PAIR (N_TOK*TOPK)   // 4096
#define B_SZ  64
#define OUT_SZ 10

typedef __attribute__((ext_vector_type(8))) short short8_t;   // 8 bf16 (4 VGPRs)
typedef __attribute__((ext_vector_type(4))) float f32x4;

// ---------------- workspace layout (bytes) ----------------
static constexpr size_t WS_TKIDX   = 0;         // int[4096]
static constexpr size_t WS_TKGATE  = 16384;     // float[4096]
static constexpr size_t WS_COUNTS  = 32768;     // int[16]
static constexpr size_t WS_OFFSETS = 33024;     // int[17]
static constexpr size_t WS_IMP     = 33536;     // float[16]
static constexpr size_t WS_PERMTOK = 33792;     // int[4096]
static constexpr size_t WS_PAIRROW = 50176;     // int[4096]
static constexpr size_t WS_XH      = 131072;                  // bf16[1024*1024] = 2 MB
static constexpr size_t WS_XL      = WS_XH + 2097152;
static constexpr size_t WS_HH      = WS_XL + 2097152;         // bf16[4096*1024] = 8 MB
static constexpr size_t WS_HL      = WS_HH + 8388608;
static constexpr size_t WS_OBUF    = WS_HL + 8388608;         // f32[4096*1024] = 16 MB
// total ~37.9 MB

// ---------------- helpers: fp32 -> bf16 split ----------------
__device__ __forceinline__ unsigned short f2bf_rn(float f) {
  unsigned int u = __float_as_uint(f);
  unsigned int r = (u + 0x7fffu + ((u >> 16) & 1u)) >> 16;
  return (unsigned short)r;
}
__device__ __forceinline__ void splitf(float f, short& h, short& l) {
  unsigned short hu = f2bf_rn(f);
  float fh = __uint_as_float(((unsigned int)hu) << 16);
  unsigned short lu = f2bf_rn(f - fh);
  h = (short)hu; l = (short)lu;
}

// ---------------- init: zero atomics ----------------
__global__ __launch_bounds__(64) void init_kernel(int* counts, float* imp) {
  int t = threadIdx.x;
  if (t < N_EXP) { counts[t] = 0; imp[t] = 0.f; }
}

// ---------------- gating: logits -> top4 -> softmax; also emit x as bf16 hi/lo ----------------
// one wave per token; 4 waves per block; grid 256
__global__ __launch_bounds__(256) void gate_kernel(
    const float* __restrict__ x, const float* __restrict__ wg,
    int* __restrict__ tk_idx, float* __restrict__ tk_gates,
    int* __restrict__ counts, float* __restrict__ imp,
    short* __restrict__ xh, short* __restrict__ xl)
{
  int wave = threadIdx.x >> 6, lane = threadIdx.x & 63;
  int n = blockIdx.x * 4 + wave;
  const float* xr = x + (size_t)n * D_DIM;
  float xv[16];
  #pragma unroll
  for (int i = 0; i < 16; i++) xv[i] = xr[lane + 64*i];

  // emit bf16 split of x (consumed by ffn_gemm1)
  #pragma unroll
  for (int i = 0; i < 16; i++) {
    short h, l; splitf(xv[i], h, l);
    xh[(size_t)n * D_DIM + lane + 64*i] = h;
    xl[(size_t)n * D_DIM + lane + 64*i] = l;
  }

  float lg[N_EXP];
  #pragma unroll
  for (int e = 0; e < N_EXP; e++) lg[e] = 0.f;
  #pragma unroll
  for (int i = 0; i < 16; i++) {
    float xvi = xv[i];
    const float4* wrow = (const float4*)(wg + (size_t)(lane + 64*i) * N_EXP);
    float4 w0 = wrow[0], w1 = wrow[1], w2 = wrow[2], w3 = wrow[3];
    lg[0]  = fmaf(xvi, w0.x, lg[0]);  lg[1]  = fmaf(xvi, w0.y, lg[1]);
    lg[2]  = fmaf(xvi, w0.z, lg[2]);  lg[3]  = fmaf(xvi, w0.w, lg[3]);
    lg[4]  = fmaf(xvi, w1.x, lg[4]);  lg[5]  = fmaf(xvi, w1.y, lg[5]);
    lg[6]  = fmaf(xvi, w1.z, lg[6]);  lg[7]  = fmaf(xvi, w1.w, lg[7]);
    lg[8]  = fmaf(xvi, w2.x, lg[8]);  lg[9]  = fmaf(xvi, w2.y, lg[9]);
    lg[10] = fmaf(xvi, w2.z, lg[10]); lg[11] = fmaf(xvi, w2.w, lg[11]);
    lg[12] = fmaf(xvi, w3.x, lg[12]); lg[13] = fmaf(xvi, w3.y, lg[13]);
    lg[14] = fmaf(xvi, w3.z, lg[14]); lg[15] = fmaf(xvi, w3.w, lg[15]);
  }
  #pragma unroll
  for (int e = 0; e < N_EXP; e++) {
    float s = lg[e];
    #pragma unroll
    for (int off = 32; off; off >>= 1) s += __shfl_xor(s, off);
    lg[e] = s;
  }

  // top-4; ties -> smallest index (matches jax.lax.top_k)
  float tv[TOPK]; int ti[TOPK];
  #pragma unroll
  for (int k = 0; k < TOPK; k++) {
    float mv = -3.4e38f; int mi = 0;
    #pragma unroll
    for (int e = 0; e < N_EXP; e++) if (lg[e] > mv) { mv = lg[e]; mi = e; }
    tv[k] = mv; ti[k] = mi; lg[mi] = -3.4e38f;
  }
  float mx = tv[0];
  float ex[TOPK]; float ssum = 0.f;
  #pragma unroll
  for (int k = 0; k < TOPK; k++) { ex[k] = expf(tv[k] - mx); ssum += ex[k]; }
  float inv = 1.f / ssum;

  if (lane < TOPK) {
    tk_idx  [n*TOPK + lane] = ti[lane];
    tk_gates[n*TOPK + lane] = ex[lane] * inv;
  }
  if (lane == 0) {
    #pragma unroll
    for (int k = 0; k < TOPK; k++) {
      atomicAdd(&counts[ti[k]], 1);
      atomicAdd(&imp[ti[k]], ex[k] * inv);
    }
  }
}

// ---------------- scan offsets + aux loss + scatter (single block) ----------------
__global__ __launch_bounds__(1024) void scan_scatter_kernel(
    const int* __restrict__ counts, const float* __restrict__ imp,
    int* __restrict__ offsets, const int* __restrict__ tk_idx,
    int* __restrict__ perm_tok, int* __restrict__ pair_row,
    float* __restrict__ out)
{
  __shared__ int scur[N_EXP];
  const int tid = threadIdx.x;
  if (tid == 0) {
    int off = 0;
    for (int e = 0; e < N_EXP; e++) { offsets[e] = off; scur[e] = off; off += counts[e]; }
    offsets[N_EXP] = off;
    float mi = 0.f, ml = 0.f;
    for (int e = 0; e < N_EXP; e++) { mi += imp[e]; ml += (float)counts[e]; }
    mi *= (1.f/N_EXP); ml *= (1.f/N_EXP);
    float vi = 0.f, vl = 0.f;
    for (int e = 0; e < N_EXP; e++) {
      float di = imp[e] - mi;           vi += di*di;
      float dl = (float)counts[e] - ml; vl += dl*dl;
    }
    vi *= (1.f/(N_EXP-1)); vl *= (1.f/(N_EXP-1));   // ddof=1
    out[640] = 0.01f * (vi/(mi*mi + 1e-10f) + vl/(ml*ml + 1e-10f));
  }
  __syncthreads();
  #pragma unroll
  for (int pp = 0; pp < N_PAIR; pp += 1024) {
    int p = pp + tid;
    int e = tk_idx[p];
    int row = atomicAdd(&scur[e], 1);
    perm_tok[row] = p >> 2;
    pair_row[p] = row;
  }
}

// ---------------- grouped split-bf16 MFMA GEMM ----------------
// C[rows,1024] = A[rows,1024] @ W[e] + bias[e]  via 3-product bf16 split:
//   C ~= Ah*Bh + Ah*Bl + Al*Bh
// A pre-split to bf16 hi/lo buffers; W fp32 split in-loop.
// tile 64x128, BK=32, 256 thr = 4 waves (2x2): wave owns 32x64 (2m x 4n frags).
// Double-buffered LDS (stride-40 rows, conflict-benign), ONE barrier per iter;
// loads issued at iter top, consumed after MFMA -> nothing in flight at barrier.
template<int GATHER, int RELU, int SPLITOUT>
__global__ __launch_bounds__(256) void ffn_gemm(
    const short* __restrict__ Ah_g,
    const short* __restrict__ Al_g,
    const float* __restrict__ W,
    const float* __restrict__ bias,
    float* __restrict__ OutF,
    short* __restrict__ OutH,
    short* __restrict__ OutL,
    const int* __restrict__ offsets,
    const int* __restrict__ perm_tok)
{
  __shared__ short Ahs[2][64][40];
  __shared__ short Als[2][64][40];
  __shared__ short Bhs[2][128][40];
  __shared__ short Bls[2][128][40];   // 60 KB total

  const int e    = blockIdx.x >> 4;
  const int slot = blockIdx.x & 15;
  const int colbase = blockIdx.y * 128;
  const int row0 = offsets[e], row_end = offsets[e+1];
  const int row_start = row0 + slot * 64;
  if (row_start >= row_end) return;
  const int rows_here = min(64, row_end - row_start);

  const int tid = threadIdx.x;

  // A staging: thread -> (row r = tid/4, 8 consecutive k at (tid&3)*8)
  const int ar_ = tid >> 2;
  const int akc = (tid & 3) * 8;
  int asrc_row = row_start + min(ar_, rows_here - 1);
  if (GATHER) asrc_row = perm_tok[asrc_row];
  const short* a_base_h = Ah_g + (size_t)asrc_row * D_DIM + akc;
  const short* a_base_l = Al_g + (size_t)asrc_row * D_DIM + akc;

  // B staging: thread -> (col bn = tid&127, 16 consecutive k at (tid>>7)*16)
  const int bn  = tid & 127;
  const int bkg = tid >> 7;
  const float* b_base = W + (size_t)e * D_DIM * H_DIMN
                          + (size_t)(bkg * 16) * H_DIMN + colbase + bn;

  // wave / fragment coords
  const int lane = tid & 63;
  const int wid  = tid >> 6;
  const int wr = wid >> 1, wc = wid & 1;
  const int l16 = lane & 15, l4 = lane >> 4;
  const int koff = l4 * 8;
  const int ar0 = wr * 32 + l16;
  const int br0 = wc * 64 + l16;

  f32x4 acc[2][4];
  #pragma unroll
  for (int i = 0; i < 2; i++)
    #pragma unroll
    for (int j = 0; j < 4; j++) acc[i][j] = (f32x4)(0.f);

  short8_t av_h, av_l;
  float bpre[16];

  // ---- prologue: load + stage tile 0 into buf 0 ----
  av_h = *(const short8_t*)(a_base_h);
  av_l = *(const short8_t*)(a_base_l);
  #pragma unroll
  for (int i = 0; i < 16; i++) bpre[i] = b_base[(size_t)i * H_DIMN];
  {
    *(short8_t*)&Ahs[0][ar_][akc] = av_h;
    *(short8_t*)&Als[0][ar_][akc] = av_l;
    short8_t h0, h1, l0, l1;
    #pragma unroll
    for (int i = 0; i < 16; i++) {
      short hs, ls; splitf(bpre[i], hs, ls);
      if (i < 8) { h0[i] = hs; l0[i] = ls; }
      else       { h1[i-8] = hs; l1[i-8] = ls; }
    }
    *(short8_t*)&Bhs[0][bn][bkg*16]     = h0;
    *(short8_t*)&Bhs[0][bn][bkg*16 + 8] = h1;
    *(short8_t*)&Bls[0][bn][bkg*16]     = l0;
    *(short8_t*)&Bls[0][bn][bkg*16 + 8] = l1;
  }
  __syncthreads();

  for (int t = 0; t < 32; t++) {
    const int rb = t & 1;
    const int kk1 = (t + 1) * 32;

    // issue next tile's loads now; consumed after MFMA (latency hidden)
    if (t + 1 < 32) {
      av_h = *(const short8_t*)(a_base_h + kk1);
      av_l = *(const short8_t*)(a_base_l + kk1);
      #pragma unroll
      for (int i = 0; i < 16; i++) bpre[i] = b_base[(size_t)(kk1 + i) * H_DIMN];
    }

    // ---- fragments + 24 MFMAs from buf rb ----
    short8_t AH[2], AL[2], BH[4], BL[4];
    #pragma unroll
    for (int m = 0; m < 2; m++) {
      AH[m] = *(const short8_t*)&Ahs[rb][ar0 + m*16][koff];
      AL[m] = *(const short8_t*)&Als[rb][ar0 + m*16][koff];
    }
    #pragma unroll
    for (int n = 0; n < 4; n++) {
      BH[n] = *(const short8_t*)&Bhs[rb][br0 + n*16][koff];
      BL[n] = *(const short8_t*)&Bls[rb][br0 + n*16][koff];
    }
    #pragma unroll
    for (int n = 0; n < 4; n++)
      #pragma unroll
      for (int m = 0; m < 2; m++)
        acc[m][n] = __builtin_amdgcn_mfma_f32_16x16x32_bf16(AH[m], BH[n], acc[m][n], 0, 0, 0);
    #pragma unroll
    for (int n = 0; n < 4; n++)
      #pragma unroll
      for (int m = 0; m < 2; m++)
        acc[m][n] = __builtin_amdgcn_mfma_f32_16x16x32_bf16(AH[m], BL[n], acc[m][n], 0, 0, 0);
    #pragma unroll
    for (int n = 0; n < 4; n++)
      #pragma unroll
      for (int m = 0; m < 2; m++)
        acc[m][n] = __builtin_amdgcn_mfma_f32_16x16x32_bf16(AL[m], BH[n], acc[m][n], 0, 0, 0);

    // ---- stage next tile into the other buffer ----
    if (t + 1 < 32) {
      const int wb = rb ^ 1;
      *(short8_t*)&Ahs[wb][ar_][akc] = av_h;
      *(short8_t*)&Als[wb][ar_][akc] = av_l;
      short8_t h0, h1, l0, l1;
      #pragma unroll
      for (int i = 0; i < 16; i++) {
        short hs, ls; splitf(bpre[i], hs, ls);
        if (i < 8) { h0[i] = hs; l0[i] = ls; }
        else       { h1[i-8] = hs; l1[i-8] = ls; }
      }
      *(short8_t*)&Bhs[wb][bn][bkg*16]     = h0;
      *(short8_t*)&Bhs[wb][bn][bkg*16 + 8] = h1;
      *(short8_t*)&Bls[wb][bn][bkg*16]     = l0;
      *(short8_t*)&Bls[wb][bn][bkg*16 + 8] = l1;
      __syncthreads();
    }
  }

  // ---- epilogue: bias (+relu); fp32 store or bf16 hi/lo split store ----
  float bvals[4];
  #pragma unroll
  for (int n = 0; n < 4; n++)
    bvals[n] = bias[e * H_DIMN + colbase + wc*64 + n*16 + l16];

  #pragma unroll
  for (int m = 0; m < 2; m++) {
    #pragma unroll
    for (int n = 0; n < 4; n++) {
      const int col = colbase + wc*64 + n*16 + l16;
      #pragma unroll
      for (int j = 0; j < 4; j++) {
        int lr = wr*32 + m*16 + l4*4 + j;
        if (lr < rows_here) {
          float v = acc[m][n][j] + bvals[n];
          if (RELU) v = fmaxf(v, 0.f);
          size_t idx = (size_t)(row_start + lr) * H_DIMN + col;
          if (SPLITOUT) {
            short hs, ls; splitf(v, hs, ls);
            OutH[idx] = hs; OutL[idx] = ls;
          } else {
            OutF[idx] = v;
          }
        }
      }
    }
  }
}

// ---------------- gather per-token, sum over M, LayerNorm, scores head ----------------
__global__ __launch_bounds__(256) void moe_ln_kernel(
    const float* __restrict__ O,
    const float* __restrict__ tk_gates,
    const int* __restrict__ pair_row,
    const float* __restrict__ ln_w, const float* __restrict__ ln_b,
    const float* __restrict__ W_los, const float* __restrict__ b_los,
    float* __restrict__ out)
{
  __shared__ float fin[D_DIM];
  __shared__ float redx[256];
  __shared__ float redy[256];
  const int b = blockIdx.x, tid = threadIdx.x;
  float4 acc = make_float4(0.f,0.f,0.f,0.f);
  for (int m = 0; m < 16; m++) {
    int n = b*16 + m;
    #pragma unroll
    for (int k = 0; k < TOPK; k++) {
      int p = n*TOPK + k;
      float g = tk_gates[p];
      int row = pair_row[p];
      float4 v = *(const float4*)&O[(size_t)row*D_DIM + tid*4];
      acc.x = fmaf(g, v.x, acc.x);
      acc.y = fmaf(g, v.y, acc.y);
      acc.z = fmaf(g, v.z, acc.z);
      acc.w = fmaf(g, v.w, acc.w);
    }
  }
  float s  = acc.x + acc.y + acc.z + acc.w;
  float s2 = acc.x*acc.x + acc.y*acc.y + acc.z*acc.z + acc.w*acc.w;
  redx[tid] = s; redy[tid] = s2;
  __syncthreads();
  for (int off = 128; off > 0; off >>= 1) {
    if (tid < off) { redx[tid] += redx[tid+off]; redy[tid] += redy[tid+off]; }
    __syncthreads();
  }
  float mean = redx[0] * (1.f/D_DIM);
  float var  = redy[0] * (1.f/D_DIM) - mean*mean;   // ddof=0
  float rstd = rsqrtf(var + 1e-5f);

  int d0 = tid*4;
  fin[d0+0] = (acc.x - mean)*rstd*ln_w[d0+0] + ln_b[d0+0];
  fin[d0+1] = (acc.y - mean)*rstd*ln_w[d0+1] + ln_b[d0+1];
  fin[d0+2] = (acc.z - mean)*rstd*ln_w[d0+2] + ln_b[d0+2];
  fin[d0+3] = (acc.w - mean)*rstd*ln_w[d0+3] + ln_b[d0+3];
  __syncthreads();

  // scores head: all 4 waves participate (o strided by wave)
  const int wv = tid >> 6, ln = tid & 63;
  for (int o = wv; o < OUT_SZ; o += 4) {
    float p = 0.f;
    for (int d = ln; d < D_DIM; d += 64) p = fmaf(fin[d], W_los[d*OUT_SZ + o], p);
    #pragma unroll
    for (int off = 32; off; off >>= 1) p += __shfl_xor(p, off);
    if (ln == 0) out[b*OUT_SZ + o] = p + b_los[o];
  }
}

// ---------------- pred_loss = mean((scores - true_y)^2) ----------------
__global__ __launch_bounds__(256) void pred_kernel(
    const float* __restrict__ true_y, float* __restrict__ out)
{
  __shared__ float red[256];
  int tid = threadIdx.x;
  float s = 0.f;
  for (int i = tid; i < B_SZ*OUT_SZ; i += 256) {
    float df = out[i] - true_y[i];
    s = fmaf(df, df, s);
  }
  red[tid] = s;
  __syncthreads();
  for (int off = 128; off > 0; off >>= 1) {
    if (tid < off) red[tid] += red[tid+off];
    __syncthreads();
  }
  if (tid == 0) out[641] = red[0] * (1.f/(B_SZ*OUT_SZ));
}

// ---------------- launch ----------------
extern "C" void kernel_launch(void* const* d_in, const int* in_sizes, int n_in,
                              void* d_out, int out_size, void* d_ws, size_t ws_size,
                              hipStream_t stream) {
  const float* x      = (const float*)d_in[0];
  const float* wg     = (const float*)d_in[1];
  const float* W1     = (const float*)d_in[2];
  const float* b1     = (const float*)d_in[3];
  const float* W2     = (const float*)d_in[4];
  const float* b2     = (const float*)d_in[5];
  const float* ln_w   = (const float*)d_in[6];
  const float* ln_b   = (const float*)d_in[7];
  const float* W_los  = (const float*)d_in[8];
  const float* b_los  = (const float*)d_in[9];
  const float* true_y = (const float*)d_in[10];
  float* out = (float*)d_out;
  char* ws = (char*)d_ws;

  int*   tk_idx   = (int*)  (ws + WS_TKIDX);
  float* tk_gates = (float*)(ws + WS_TKGATE);
  int*   counts   = (int*)  (ws + WS_COUNTS);
  int*   offsets  = (int*)  (ws + WS_OFFSETS);
  float* imp      = (float*)(ws + WS_IMP);
  int*   perm_tok = (int*)  (ws + WS_PERMTOK);
  int*   pair_row = (int*)  (ws + WS_PAIRROW);
  short* xh       = (short*)(ws + WS_XH);
  short* xl       = (short*)(ws + WS_XL);
  short* Hh       = (short*)(ws + WS_HH);
  short* Hl       = (short*)(ws + WS_HL);
  float* Obuf     = (float*)(ws + WS_OBUF);

  init_kernel<<<1, 64, 0, stream>>>(counts, imp);
  gate_kernel<<<256, 256, 0, stream>>>(x, wg, tk_idx, tk_gates, counts, imp, xh, xl);
  scan_scatter_kernel<<<1, 1024, 0, stream>>>(counts, imp, offsets, tk_idx,
                                              perm_tok, pair_row, out);
  // GEMM1: gathered x (hi/lo) @ W1 -> relu -> split-store Hh/Hl
  ffn_gemm<1,1,1><<<dim3(256, 8), 256, 0, stream>>>(
      xh, xl, W1, b1, nullptr, Hh, Hl, offsets, perm_tok);
  // GEMM2: Hh/Hl @ W2 -> fp32 Obuf
  ffn_gemm<0,0,0><<<dim3(256, 8), 256, 0, stream>>>(
      Hh, Hl, W2, b2, Obuf, nullptr, nullptr, offsets, perm_tok);
  moe_ln_kernel<<<64, 256, 0, stream>>>(Obuf, tk_gates, pair_row, ln_w, ln_b, W_los, b_los, out);
  pred_kernel<<<1, 256, 0, stream>>>(true_y, out);
}

// Round 5
// 362.002 us; speedup vs baseline: 1.6454x; 1.6454x over previous
//
#include <hip/hip_runtime.h>
#include <hip/hip_bf16.h>

// Problem constants
#define D_DIM 1024
#define H_DIMN 1024
#define N_TOK 1024
#define N_EXP 16
#define TOPK  4
#define N_PAIR (N_TOK*TOPK)   // 4096
#define B_SZ  64
#define OUT_SZ 10
#define MAX_TILES 48

typedef __attribute__((ext_vector_type(8))) short short8_t;   // 8 bf16
typedef __attribute__((ext_vector_type(4))) float f32x4;

// ---------------- workspace layout (bytes); total ~101 MB ----------------
static constexpr size_t WS_TKIDX   = 0;         // int[4096]
static constexpr size_t WS_TKGATE  = 16384;     // float[4096]
static constexpr size_t WS_OFFSETS = 32768;     // int[17]
static constexpr size_t WS_TE      = 33024;     // int[48]
static constexpr size_t WS_TRS     = 33280;     // int[48]
static constexpr size_t WS_NTILE   = 33536;     // int[1]
static constexpr size_t WS_PERMTOK = 33792;     // int[4096]
static constexpr size_t WS_PAIRROW = 50176;     // int[4096]
static constexpr size_t WS_XS      = 131072;    // short[1024*2048]  (4 MB)  [tok][kb32][2][32]
static constexpr size_t WS_HS      = 4325376;   // short[4096*2048]  (16 MB) [row][kb32][2][32]
static constexpr size_t WS_OBUF    = 21102592;  // float[4096*1024]  (16 MB)
static constexpr size_t WS_WT      = 37879808;  // short[16*32*1024*2*32] (64 MB, reused W1/W2)

// ---------------- fp32 -> bf16 split ----------------
__device__ __forceinline__ unsigned short f2bf_rn(float f) {
  unsigned int u = __float_as_uint(f);
  unsigned int r = (u + 0x7fffu + ((u >> 16) & 1u)) >> 16;
  return (unsigned short)r;
}
__device__ __forceinline__ void splitf(float f, short& h, short& l) {
  unsigned short hu = f2bf_rn(f);
  float fh = __uint_as_float(((unsigned int)hu) << 16);
  unsigned short lu = f2bf_rn(f - fh);
  h = (short)hu; l = (short)lu;
}

// ---------------- split+transpose W: [e][k][n] f32 -> [e][kb][n][2][32] bf16 ----------------
// grid (8 n-tiles, 32 kb, 16 e), 256 thr
__global__ __launch_bounds__(256) void split_w_kernel(
    const float* __restrict__ W, short* __restrict__ WT)
{
  __shared__ float tb[32][132];
  const int nt = blockIdx.x, kb = blockIdx.y, e = blockIdx.z;
  const int t = threadIdx.x;
  const float* src = W + ((size_t)e << 20) + (size_t)(kb * 32) * 1024 + nt * 128;
  // coalesced read: 32 rows x 128 cols
  const int rk = t >> 3;
  const int rc = (t & 7) * 16;
  #pragma unroll
  for (int j = 0; j < 4; j++)
    *(float4*)&tb[rk][rc + j*4] = *(const float4*)(src + (size_t)rk * 1024 + rc + j*4);
  __syncthreads();
  // transpose out: thread -> (col n = t>>1, k-half kh = (t&1)*16)
  const int n  = t >> 1;
  const int kh = (t & 1) * 16;
  short h[16], l[16];
  #pragma unroll
  for (int i = 0; i < 16; i++) splitf(tb[kh + i][n], h[i], l[i]);
  short* dst = WT + (((size_t)e * 32 + kb) * 1024 + nt * 128 + n) * 64;
  *(short8_t*)(dst + kh)          = *(short8_t*)&h[0];
  *(short8_t*)(dst + kh + 8)      = *(short8_t*)&h[8];
  *(short8_t*)(dst + 32 + kh)     = *(short8_t*)&l[0];
  *(short8_t*)(dst + 32 + kh + 8) = *(short8_t*)&l[8];
}

// ---------------- gating + split-x ----------------
// one wave per token; 4 waves/block; grid 256. No global atomics.
__global__ __launch_bounds__(256) void gate_kernel(
    const float* __restrict__ x, const float* __restrict__ wg,
    int* __restrict__ tk_idx, float* __restrict__ tk_gates,
    short* __restrict__ xs)
{
  int wave = threadIdx.x >> 6, lane = threadIdx.x & 63;
  int n = blockIdx.x * 4 + wave;
  const float* xr = x + (size_t)n * D_DIM + lane * 16;   // 16 consecutive k per lane
  float xv[16];
  #pragma unroll
  for (int j = 0; j < 4; j++) {
    float4 v = *(const float4*)(xr + j*4);
    xv[j*4+0] = v.x; xv[j*4+1] = v.y; xv[j*4+2] = v.z; xv[j*4+3] = v.w;
  }

  // emit blocked split x: lane covers k = lane*16..+15 -> kb = lane>>1, kh = (lane&1)*16
  {
    short h[16], l[16];
    #pragma unroll
    for (int i = 0; i < 16; i++) splitf(xv[i], h[i], l[i]);
    short* base = xs + (size_t)n * 2048 + (lane >> 1) * 64 + (lane & 1) * 16;
    *(short8_t*)(base)          = *(short8_t*)&h[0];
    *(short8_t*)(base + 8)      = *(short8_t*)&h[8];
    *(short8_t*)(base + 32)     = *(short8_t*)&l[0];
    *(short8_t*)(base + 32 + 8) = *(short8_t*)&l[8];
  }

  float lg[N_EXP];
  #pragma unroll
  for (int e = 0; e < N_EXP; e++) lg[e] = 0.f;
  #pragma unroll
  for (int i = 0; i < 16; i++) {
    float xvi = xv[i];
    const float4* wrow = (const float4*)(wg + (size_t)(lane * 16 + i) * N_EXP);
    float4 w0 = wrow[0], w1 = wrow[1], w2 = wrow[2], w3 = wrow[3];
    lg[0]  = fmaf(xvi, w0.x, lg[0]);  lg[1]  = fmaf(xvi, w0.y, lg[1]);
    lg[2]  = fmaf(xvi, w0.z, lg[2]);  lg[3]  = fmaf(xvi, w0.w, lg[3]);
    lg[4]  = fmaf(xvi, w1.x, lg[4]);  lg[5]  = fmaf(xvi, w1.y, lg[5]);
    lg[6]  = fmaf(xvi, w1.z, lg[6]);  lg[7]  = fmaf(xvi, w1.w, lg[7]);
    lg[8]  = fmaf(xvi, w2.x, lg[8]);  lg[9]  = fmaf(xvi, w2.y, lg[9]);
    lg[10] = fmaf(xvi, w2.z, lg[10]); lg[11] = fmaf(xvi, w2.w, lg[11]);
    lg[12] = fmaf(xvi, w3.x, lg[12]); lg[13] = fmaf(xvi, w3.y, lg[13]);
    lg[14] = fmaf(xvi, w3.z, lg[14]); lg[15] = fmaf(xvi, w3.w, lg[15]);
  }
  #pragma unroll
  for (int e = 0; e < N_EXP; e++) {
    float s = lg[e];
    #pragma unroll
    for (int off = 32; off; off >>= 1) s += __shfl_xor(s, off);
    lg[e] = s;
  }

  float tv[TOPK]; int ti[TOPK];
  #pragma unroll
  for (int k = 0; k < TOPK; k++) {
    float mv = -3.4e38f; int mi = 0;
    #pragma unroll
    for (int e = 0; e < N_EXP; e++) if (lg[e] > mv) { mv = lg[e]; mi = e; }
    tv[k] = mv; ti[k] = mi; lg[mi] = -3.4e38f;
  }
  float mx = tv[0];
  float ex[TOPK]; float ssum = 0.f;
  #pragma unroll
  for (int k = 0; k < TOPK; k++) { ex[k] = expf(tv[k] - mx); ssum += ex[k]; }
  float inv = 1.f / ssum;

  if (lane < TOPK) {
    tk_idx  [n*TOPK + lane] = ti[lane];
    tk_gates[n*TOPK + lane] = ex[lane] * inv;
  }
}

// ---------------- scan + loss + scatter + tile table (1 block) ----------------
__global__ __launch_bounds__(1024) void scan_scatter_kernel(
    const int* __restrict__ tk_idx, const float* __restrict__ tk_gates,
    int* __restrict__ offsets, int* __restrict__ perm_tok, int* __restrict__ pair_row,
    int* __restrict__ te, int* __restrict__ trs, int* __restrict__ ntile,
    float* __restrict__ out)
{
  __shared__ int cnt[N_EXP];
  __shared__ float fimp[N_EXP];
  __shared__ int cur[N_EXP];
  const int tid = threadIdx.x;
  if (tid < N_EXP) { cnt[tid] = 0; fimp[tid] = 0.f; }
  __syncthreads();
  #pragma unroll
  for (int pp = 0; pp < N_PAIR; pp += 1024) {
    int p = pp + tid;
    int e = tk_idx[p];
    atomicAdd(&cnt[e], 1);
    atomicAdd(&fimp[e], tk_gates[p]);
  }
  __syncthreads();
  if (tid == 0) {
    int off = 0;
    for (int e = 0; e < N_EXP; e++) { offsets[e] = off; cur[e] = off; off += cnt[e]; }
    offsets[N_EXP] = off;
    float mi = 0.f, ml = 0.f;
    for (int e = 0; e < N_EXP; e++) { mi += fimp[e]; ml += (float)cnt[e]; }
    mi *= (1.f/N_EXP); ml *= (1.f/N_EXP);
    float vi = 0.f, vl = 0.f;
    for (int e = 0; e < N_EXP; e++) {
      float di = fimp[e] - mi;          vi += di*di;
      float dl = (float)cnt[e] - ml;    vl += dl*dl;
    }
    vi *= (1.f/(N_EXP-1)); vl *= (1.f/(N_EXP-1));   // ddof=1
    out[640] = 0.01f * (vi/(mi*mi + 1e-10f) + vl/(ml*ml + 1e-10f));
    out[641] = 0.f;   // MSE accumulator (moe_ln atomics)
    int T = 0;
    for (int e = 0; e < N_EXP; e++) {
      int nt = (cnt[e] + 127) >> 7;
      for (int s = 0; s < nt; s++) { te[T] = e; trs[T] = offsets[e] + s*128; T++; }
    }
    *ntile = T;
  }
  __syncthreads();
  #pragma unroll
  for (int pp = 0; pp < N_PAIR; pp += 1024) {
    int p = pp + tid;
    int row = atomicAdd(&cur[tk_idx[p]], 1);
    perm_tok[row] = p >> 2;
    pair_row[p] = row;
  }
}

// ---------------- grouped split-bf16 MFMA GEMM ----------------
// C[rows,1024] = A @ W[e] + bias[e], 3-product split (Ah*Bh + Ah*Bl + Al*Bh).
// A: [row][kb][2][32] bf16 pre-split; B: WT[e][kb][n][2][32] pre-split+transposed.
// tile 128x128, BK=32 (= one kb), 256 thr = 4 waves (2x2), wave 64x64 (4x4 frags).
// LDS stride 40 shorts + k-chunk rotation swizzle: all accesses <=2-way (free).
// 2-barrier loop, reg-prefetch issued right after bar1.
template<int GATHER, int RELU, int SPLITOUT>
__global__ __launch_bounds__(256) void ffn_gemm(
    const short* __restrict__ As,
    const short* __restrict__ WT,
    const float* __restrict__ bias,
    float* __restrict__ OutF,
    short* __restrict__ OutS,
    const int* __restrict__ offsets,
    const int* __restrict__ perm_tok,
    const int* __restrict__ te, const int* __restrict__ trs,
    const int* __restrict__ ntile)
{
  __shared__ short Ah[128][40], Al[128][40], Bh[128][40], Bl[128][40];  // 40 KB

  const int ti = blockIdx.x;
  if (ti >= *ntile) return;
  const int e = te[ti];
  const int row_start = trs[ti];
  const int rows_here = min(128, offsets[e+1] - row_start);
  const int colbase = blockIdx.y * 128;
  const int tid = threadIdx.x;

  // staging coords: thread -> (lds row srow, hi/lo plane ssel), 32 shorts each
  const int srow = tid >> 1;
  const int ssel = tid & 1;
  int arow_g = row_start + min(srow, rows_here - 1);
  if (GATHER) arow_g = perm_tok[arow_g];
  const short* a_ptr = As + (size_t)arow_g * 2048 + ssel * 32;
  const short* b_ptr = WT + (size_t)e * 2097152 + (size_t)(colbase + srow) * 64 + ssel * 32;

  short* aw = ssel ? &Al[srow][0] : &Ah[srow][0];
  short* bw = ssel ? &Bl[srow][0] : &Bh[srow][0];
  const int rotW = (srow >> 3) & 3;

  // wave/frag coords
  const int lane = tid & 63;
  const int wid  = tid >> 6;
  const int wr = wid >> 1, wc = wid & 1;
  const int l16 = lane & 15, l4 = lane >> 4;
  const int ar0 = wr * 64 + l16;
  const int br0 = wc * 64 + l16;

  // per-frag swizzled read offsets (loop-invariant)
  int aoff[4], boff[4];
  #pragma unroll
  for (int m = 0; m < 4; m++) {
    int R = ar0 + m * 16;
    aoff[m] = R * 40 + ((l4 + (R >> 3)) & 3) * 8;
    int S = br0 + m * 16;
    boff[m] = S * 40 + ((l4 + (S >> 3)) & 3) * 8;
  }
  const short* Ah0 = &Ah[0][0]; const short* Al0 = &Al[0][0];
  const short* Bh0 = &Bh[0][0]; const short* Bl0 = &Bl[0][0];

  f32x4 acc[4][4];
  #pragma unroll
  for (int i = 0; i < 4; i++)
    #pragma unroll
    for (int j = 0; j < 4; j++) acc[i][j] = (f32x4)(0.f);

  short8_t rA[4], rB[4];
  #pragma unroll
  for (int j = 0; j < 4; j++) {
    rA[j] = *(const short8_t*)(a_ptr + j * 8);
    rB[j] = *(const short8_t*)(b_ptr + j * 8);
  }

  for (int t = 0; t < 32; t++) {
    // stage regs -> LDS (rotated chunk slots)
    #pragma unroll
    for (int j = 0; j < 4; j++) {
      *(short8_t*)(aw + ((j + rotW) & 3) * 8) = rA[j];
      *(short8_t*)(bw + ((j + rotW) & 3) * 8) = rB[j];
    }
    __syncthreads();

    // prefetch next kb (lands during frag reads + MFMA)
    if (t < 31) {
      const short* ap = a_ptr + (t + 1) * 64;
      const short* bp = b_ptr + (size_t)(t + 1) * 65536;
      #pragma unroll
      for (int j = 0; j < 4; j++) {
        rA[j] = *(const short8_t*)(ap + j * 8);
        rB[j] = *(const short8_t*)(bp + j * 8);
      }
    }

    short8_t AH[4], AL[4], BH[4], BL[4];
    #pragma unroll
    for (int m = 0; m < 4; m++) {
      AH[m] = *(const short8_t*)(Ah0 + aoff[m]);
      AL[m] = *(const short8_t*)(Al0 + aoff[m]);
      BH[m] = *(const short8_t*)(Bh0 + boff[m]);
      BL[m] = *(const short8_t*)(Bl0 + boff[m]);
    }
    #pragma unroll
    for (int n = 0; n < 4; n++)
      #pragma unroll
      for (int m = 0; m < 4; m++)
        acc[m][n] = __builtin_amdgcn_mfma_f32_16x16x32_bf16(AH[m], BH[n], acc[m][n], 0, 0, 0);
    #pragma unroll
    for (int n = 0; n < 4; n++)
      #pragma unroll
      for (int m = 0; m < 4; m++)
        acc[m][n] = __builtin_amdgcn_mfma_f32_16x16x32_bf16(AH[m], BL[n], acc[m][n], 0, 0, 0);
    #pragma unroll
    for (int n = 0; n < 4; n++)
      #pragma unroll
      for (int m = 0; m < 4; m++)
        acc[m][n] = __builtin_amdgcn_mfma_f32_16x16x32_bf16(AL[m], BH[n], acc[m][n], 0, 0, 0);
    __syncthreads();
  }

  // epilogue
  float bvals[4];
  #pragma unroll
  for (int n = 0; n < 4; n++)
    bvals[n] = bias[e * H_DIMN + colbase + wc*64 + n*16 + l16];

  #pragma unroll
  for (int m = 0; m < 4; m++) {
    #pragma unroll
    for (int n = 0; n < 4; n++) {
      const int col = colbase + wc*64 + n*16 + l16;
      #pragma unroll
      for (int j = 0; j < 4; j++) {
        int lr = wr*64 + m*16 + l4*4 + j;
        if (lr < rows_here) {
          float v = acc[m][n][j] + bvals[n];
          if (RELU) v = fmaxf(v, 0.f);
          size_t row = (size_t)(row_start + lr);
          if (SPLITOUT) {
            short hs, ls; splitf(v, hs, ls);
            size_t idx = row * 2048 + (col >> 5) * 64 + (col & 31);
            OutS[idx]      = hs;
            OutS[idx + 32] = ls;
          } else {
            OutF[row * H_DIMN + col] = v;
          }
        }
      }
    }
  }
}

// ---------------- gather, sum over M, LayerNorm, scores head, MSE ----------------
__global__ __launch_bounds__(256) void moe_ln_kernel(
    const float* __restrict__ O,
    const float* __restrict__ tk_gates,
    const int* __restrict__ pair_row,
    const float* __restrict__ ln_w, const float* __restrict__ ln_b,
    const float* __restrict__ W_los, const float* __restrict__ b_los,
    const float* __restrict__ true_y,
    float* __restrict__ out)
{
  __shared__ float fin[D_DIM];
  __shared__ float redx[256];
  __shared__ float redy[256];
  const int b = blockIdx.x, tid = threadIdx.x;
  float4 acc = make_float4(0.f,0.f,0.f,0.f);
  for (int m = 0; m < 16; m++) {
    int n = b*16 + m;
    #pragma unroll
    for (int k = 0; k < TOPK; k++) {
      int p = n*TOPK + k;
      float g = tk_gates[p];
      int row = pair_row[p];
      float4 v = *(const float4*)&O[(size_t)row*D_DIM + tid*4];
      acc.x = fmaf(g, v.x, acc.x);
      acc.y = fmaf(g, v.y, acc.y);
      acc.z = fmaf(g, v.z, acc.z);
      acc.w = fmaf(g, v.w, acc.w);
    }
  }
  float s  = acc.x + acc.y + acc.z + acc.w;
  float s2 = acc.x*acc.x + acc.y*acc.y + acc.z*acc.z + acc.w*acc.w;
  redx[tid] = s; redy[tid] = s2;
  __syncthreads();
  for (int off = 128; off > 0; off >>= 1) {
    if (tid < off) { redx[tid] += redx[tid+off]; redy[tid] += redy[tid+off]; }
    __syncthreads();
  }
  float mean = redx[0] * (1.f/D_DIM);
  float var  = redy[0] * (1.f/D_DIM) - mean*mean;   // ddof=0
  float rstd = rsqrtf(var + 1e-5f);

  int d0 = tid*4;
  fin[d0+0] = (acc.x - mean)*rstd*ln_w[d0+0] + ln_b[d0+0];
  fin[d0+1] = (acc.y - mean)*rstd*ln_w[d0+1] + ln_b[d0+1];
  fin[d0+2] = (acc.z - mean)*rstd*ln_w[d0+2] + ln_b[d0+2];
  fin[d0+3] = (acc.w - mean)*rstd*ln_w[d0+3] + ln_b[d0+3];
  __syncthreads();

  const int wv = tid >> 6, ln = tid & 63;
  for (int o = wv; o < OUT_SZ; o += 4) {
    float p = 0.f;
    for (int d = ln; d < D_DIM; d += 64) p = fmaf(fin[d], W_los[d*OUT_SZ + o], p);
    #pragma unroll
    for (int off = 32; off; off >>= 1) p += __shfl_xor(p, off);
    if (ln == 0) {
      float sc = p + b_los[o];
      out[b*OUT_SZ + o] = sc;
      float d = sc - true_y[b*OUT_SZ + o];
      atomicAdd(&out[641], d * d * (1.f/(B_SZ*OUT_SZ)));
    }
  }
}

// ---------------- launch ----------------
extern "C" void kernel_launch(void* const* d_in, const int* in_sizes, int n_in,
                              void* d_out, int out_size, void* d_ws, size_t ws_size,
                              hipStream_t stream) {
  const float* x      = (const float*)d_in[0];
  const float* wg     = (const float*)d_in[1];
  const float* W1     = (const float*)d_in[2];
  const float* b1     = (const float*)d_in[3];
  const float* W2     = (const float*)d_in[4];
  const float* b2     = (const float*)d_in[5];
  const float* ln_w   = (const float*)d_in[6];
  const float* ln_b   = (const float*)d_in[7];
  const float* W_los  = (const float*)d_in[8];
  const float* b_los  = (const float*)d_in[9];
  const float* true_y = (const float*)d_in[10];
  float* out = (float*)d_out;
  char* ws = (char*)d_ws;

  int*   tk_idx   = (int*)  (ws + WS_TKIDX);
  float* tk_gates = (float*)(ws + WS_TKGATE);
  int*   offsets  = (int*)  (ws + WS_OFFSETS);
  int*   te       = (int*)  (ws + WS_TE);
  int*   trs      = (int*)  (ws + WS_TRS);
  int*   ntile    = (int*)  (ws + WS_NTILE);
  int*   perm_tok = (int*)  (ws + WS_PERMTOK);
  int*   pair_row = (int*)  (ws + WS_PAIRROW);
  short* xs       = (short*)(ws + WS_XS);
  short* Hs       = (short*)(ws + WS_HS);
  float* Obuf     = (float*)(ws + WS_OBUF);
  short* WT       = (short*)(ws + WS_WT);

  // W1 -> WT (split+transpose+block)
  split_w_kernel<<<dim3(8, 32, 16), 256, 0, stream>>>(W1, WT);
  gate_kernel<<<256, 256, 0, stream>>>(x, wg, tk_idx, tk_gates, xs);
  scan_scatter_kernel<<<1, 1024, 0, stream>>>(tk_idx, tk_gates, offsets,
                                              perm_tok, pair_row, te, trs, ntile, out);
  // GEMM1: gathered xs @ WT(W1) -> relu -> split-blocked Hs
  ffn_gemm<1,1,1><<<dim3(MAX_TILES, 8), 256, 0, stream>>>(
      xs, WT, b1, nullptr, Hs, offsets, perm_tok, te, trs, ntile);
  // W2 -> WT (reuse buffer)
  split_w_kernel<<<dim3(8, 32, 16), 256, 0, stream>>>(W2, WT);
  // GEMM2: Hs @ WT(W2) -> fp32 Obuf
  ffn_gemm<0,0,0><<<dim3(MAX_TILES, 8), 256, 0, stream>>>(
      Hs, WT, b2, Obuf, nullptr, offsets, perm_tok, te, trs, ntile);
  moe_ln_kernel<<<64, 256, 0, stream>>>(Obuf, tk_gates, pair_row, ln_w, ln_b,
                                        W_los, b_los, true_y, out);
}